// Round 2
// baseline (427.871 us; speedup 1.0000x reference)
//
#include <hip/hip_runtime.h>
#include <stdint.h>

// TopoSignature via parallel Boruvka MST. Round 13: r11 structure with
// COMPILER-PINNED load pipelining.
//  - r12 lesson: source-level batching (float4 w[8]) was silently
//    re-serialized by hipcc (VGPR 28, not ~50; dur unchanged). Little's law
//    on the counters (3.0 TB/s @ ~400ns => ~1 load in flight per CU) says
//    scanA is concurrency-starved, not at a BW ceiling.
//  - Fix: __builtin_amdgcn_sched_barrier(0) fences pin an 8-deep
//    consume-then-reload pipeline (scanA) / 4-deep (scan2 need-path, scanF).
//    ~50 VGPR, under the 64 cap of launch_bounds(256,8).
//  - Tripwire: if VGPR stays < 40 the pin failed; if VGPR rises but dur
//    doesn't, ~3 TB/s is a real pattern ceiling -> pivot to symmetry.
// Lessons kept: kernel boundary = the only cheap device-wide barrier (r8:
// threadfence ticket ~50-270us/round; r10: replicated hook = 94 MB re-reads
// + 7.5M LDS conflicts). init folded in scanA; epilogue fused in final hook.

#define N        4096
#define NROUNDS  12

typedef unsigned long long u64;
typedef uint32_t u32;

#define INFK (~0ull)

struct Ws {
    u64 best[2][N];      // per-component min outgoing edge key: (wbits<<24)|(lo<<12)|hi
    u32 comp[2][N];      // vertex -> component root label
    u32 edges[2][N];     // edge slot per vertex, (lo<<12)|hi; (i<<12)|i = none
    u32 ncomp[2];
    u32 pad[14];
    u64 bm[2][N * 64];   // per-row per-lane-block bound keys: (wbits<<12)|col ; 4 MB
};

__device__ __forceinline__ u64 umin64(u64 a, u64 b) { return a < b ? a : b; }

__device__ __forceinline__ u64 shfl_xor_u64(u64 x, int off) {
    u32 lo = (u32)x, hi = (u32)(x >> 32);
    lo = (u32)__shfl_xor((int)lo, off, 64);
    hi = (u32)__shfl_xor((int)hi, off, 64);
    return ((u64)hi << 32) | lo;
}

// ---- round 1 full scan + state init. One wave per row; lane-private block
// minima (block L = cols ≡ [4L,4L+4) mod 256). 8-deep pinned pipeline. ----
__launch_bounds__(256, 8)
__global__ void scanA_k(const float* __restrict__ d1, const float* __restrict__ d2,
                        Ws* __restrict__ ws) {
    const int m = blockIdx.x >> 10;
    const int wave = threadIdx.x >> 6, lane = threadIdx.x & 63;
    const int v = ((blockIdx.x & 1023) << 2) + wave;
    const float4* __restrict__ row4 = (const float4*)((m ? d2 : d1) + (size_t)v * N);

    const u32 uv = (u32)v;
    u64 a0 = INFK, a1 = INFK, a2 = INFK, a3 = INFK;

    float4 w[8];
    #pragma unroll
    for (int j = 0; j < 8; ++j)
        w[j] = row4[lane + 64 * j];
    __builtin_amdgcn_sched_barrier(0);

    // steady state: consume chunk j, reload slot with chunk j+8 (stays ~8 deep)
    #pragma unroll
    for (int j = 0; j < 8; ++j) {
        const u32 c0 = (u32)(4 * (lane + 64 * j));
        float4 t = w[j];
        if (c0 + 0 != uv) a0 = umin64(a0, (((u64)__float_as_uint(t.x)) << 12) | (c0 + 0));
        if (c0 + 1 != uv) a1 = umin64(a1, (((u64)__float_as_uint(t.y)) << 12) | (c0 + 1));
        if (c0 + 2 != uv) a2 = umin64(a2, (((u64)__float_as_uint(t.z)) << 12) | (c0 + 2));
        if (c0 + 3 != uv) a3 = umin64(a3, (((u64)__float_as_uint(t.w)) << 12) | (c0 + 3));
        w[j] = row4[lane + 64 * (8 + j)];
        __builtin_amdgcn_sched_barrier(0);
    }
    #pragma unroll
    for (int j = 0; j < 8; ++j) {
        const u32 c0 = (u32)(4 * (lane + 64 * (8 + j)));
        float4 t = w[j];
        if (c0 + 0 != uv) a0 = umin64(a0, (((u64)__float_as_uint(t.x)) << 12) | (c0 + 0));
        if (c0 + 1 != uv) a1 = umin64(a1, (((u64)__float_as_uint(t.y)) << 12) | (c0 + 1));
        if (c0 + 2 != uv) a2 = umin64(a2, (((u64)__float_as_uint(t.z)) << 12) | (c0 + 2));
        if (c0 + 3 != uv) a3 = umin64(a3, (((u64)__float_as_uint(t.w)) << 12) | (c0 + 3));
    }
    u64 bmin = umin64(umin64(a0, a1), umin64(a2, a3));
    ws->bm[m][(size_t)v * 64 + lane] = bmin;      // coalesced 512 B store

    u64 rowmin = bmin;
    #pragma unroll
    for (int off = 1; off <= 32; off <<= 1)
        rowmin = umin64(rowmin, shfl_xor_u64(rowmin, off));

    if (lane == 0) {
        u32 u  = (u32)rowmin & 0xFFFu;
        u64 wb = rowmin >> 12;
        u32 lo = min(uv, u), hi = max(uv, u);
        ws->best[m][v]  = (wb << 24) | ((u64)lo << 12) | (u64)hi;  // comp==v, unique writer
        ws->comp[m][v]  = uv;                                       // init fold
        ws->edges[m][v] = (uv << 12) | uv;                          // diag sentinel
    }
    if (threadIdx.x == 0 && (blockIdx.x & 1023) == 0)
        ws->ncomp[m] = (u32)N;
}

// ---- rounds 2+: bound-table scan. One wave per row, lane = block. ----
__launch_bounds__(256, 8)
__global__ void scan2_k(const float* __restrict__ d1, const float* __restrict__ d2,
                        Ws* __restrict__ ws) {
    const int m = blockIdx.x >> 10;
    if (ws->ncomp[m] <= 1u) return;
    const int wave = threadIdx.x >> 6, lane = threadIdx.x & 63;
    const int v = ((blockIdx.x & 1023) << 2) + wave;

    const float* __restrict__ dm = m ? d2 : d1;
    const u32*   __restrict__ cm = ws->comp[m];
    u64* __restrict__ bmrow = ws->bm[m] + (size_t)v * 64;

    const u32 cv = cm[v];
    u64 key = bmrow[lane];
    bool cross = false;
    if (key != INFK) cross = (cm[(u32)key & 0xFFFu] != cv);

    // best cross candidate among stored block mins (exact entries)
    u64 kb = cross ? key : INFK;
    #pragma unroll
    for (int off = 1; off <= 32; off <<= 1)
        kb = umin64(kb, shfl_xor_u64(kb, off));

    // intra bound undercutting kb -> block may hide a smaller cross entry
    const bool need = (!cross) && (key < kb);
    u64 nm = INFK;
    if (need) {
        const float4* __restrict__ row4 = (const float4*)(dm + (size_t)v * N);
        const uint4*  __restrict__ c4   = (const uint4*)cm;
        u64 n0 = INFK, n1 = INFK, n2 = INFK, n3 = INFK;
        float4 w[4];
        uint4  cu[4];
        #pragma unroll
        for (int j = 0; j < 4; ++j) {
            w[j]  = row4[lane + 64 * j];
            cu[j] = c4[lane + 64 * j];
        }
        __builtin_amdgcn_sched_barrier(0);
        #pragma unroll
        for (int j = 0; j < 12; ++j) {
            const int s = j & 3;
            const u32 c0 = (u32)(4 * (lane + 64 * j));
            float4 t = w[s];
            uint4  cc = cu[s];
            if (cc.x != cv) n0 = umin64(n0, (((u64)__float_as_uint(t.x)) << 12) | (c0 + 0));
            if (cc.y != cv) n1 = umin64(n1, (((u64)__float_as_uint(t.y)) << 12) | (c0 + 1));
            if (cc.z != cv) n2 = umin64(n2, (((u64)__float_as_uint(t.z)) << 12) | (c0 + 2));
            if (cc.w != cv) n3 = umin64(n3, (((u64)__float_as_uint(t.w)) << 12) | (c0 + 3));
            w[s]  = row4[lane + 64 * (j + 4)];
            cu[s] = c4[lane + 64 * (j + 4)];
            __builtin_amdgcn_sched_barrier(0);
        }
        #pragma unroll
        for (int j = 12; j < 16; ++j) {
            const int s = j & 3;
            const u32 c0 = (u32)(4 * (lane + 64 * j));
            float4 t = w[s];
            uint4  cc = cu[s];
            if (cc.x != cv) n0 = umin64(n0, (((u64)__float_as_uint(t.x)) << 12) | (c0 + 0));
            if (cc.y != cv) n1 = umin64(n1, (((u64)__float_as_uint(t.y)) << 12) | (c0 + 1));
            if (cc.z != cv) n2 = umin64(n2, (((u64)__float_as_uint(t.z)) << 12) | (c0 + 2));
            if (cc.w != cv) n3 = umin64(n3, (((u64)__float_as_uint(t.w)) << 12) | (c0 + 3));
        }
        nm = umin64(umin64(n0, n1), umin64(n2, n3));
        bmrow[lane] = nm;    // tightened bound: block's current min-cross key
    }
    u64 kb2 = need ? nm : INFK;
    #pragma unroll
    for (int off = 1; off <= 32; off <<= 1)
        kb2 = umin64(kb2, shfl_xor_u64(kb2, off));

    u64 fin = umin64(kb, kb2);
    if (lane == 0 && fin != INFK) {
        u32 u  = (u32)fin & 0xFFFu;
        u64 wb = fin >> 12;
        u32 lo = min((u32)v, u), hi = max((u32)v, u);
        u64 g  = (wb << 24) | ((u64)lo << 12) | (u64)hi;
        if (g < ws->best[m][cv])
            atomicMin(&ws->best[m][cv], g);
    }
}

// ---- fallback full scan (ws too small for bound table) ----
__launch_bounds__(256, 8)
__global__ void scanF_k(const float* __restrict__ d1, const float* __restrict__ d2,
                        Ws* __restrict__ ws, int first) {
    const int m = blockIdx.x >> 10;
    if (!first && ws->ncomp[m] <= 1u) return;
    const int wave = threadIdx.x >> 6, lane = threadIdx.x & 63;
    const int v = ((blockIdx.x & 1023) << 2) + wave;
    const float* __restrict__ dm = m ? d2 : d1;
    const u32*   __restrict__ cm = ws->comp[m];
    const float4* __restrict__ row4 = (const float4*)(dm + (size_t)v * N);
    const uint4*  __restrict__ c4   = (const uint4*)cm;
    const u32 cv = first ? (u32)v : cm[v];
    u64 k0 = INFK, k1 = INFK, k2 = INFK, k3 = INFK;
    float4 w[4];
    uint4  cu[4];
    #pragma unroll
    for (int j = 0; j < 4; ++j) {
        w[j] = row4[lane + 64 * j];
        if (!first) cu[j] = c4[lane + 64 * j];
    }
    __builtin_amdgcn_sched_barrier(0);
    #pragma unroll
    for (int j = 0; j < 16; ++j) {
        const int s = j & 3;
        const u32 c0 = (u32)(4 * (lane + 64 * j));
        float4 t = w[s];
        bool x0, x1, x2, x3;
        if (first) {
            x0 = (c0+0 != cv); x1 = (c0+1 != cv); x2 = (c0+2 != cv); x3 = (c0+3 != cv);
        } else {
            x0 = (cu[s].x != cv); x1 = (cu[s].y != cv); x2 = (cu[s].z != cv); x3 = (cu[s].w != cv);
        }
        if (x0) k0 = umin64(k0, (((u64)__float_as_uint(t.x)) << 12) | (c0 + 0));
        if (x1) k1 = umin64(k1, (((u64)__float_as_uint(t.y)) << 12) | (c0 + 1));
        if (x2) k2 = umin64(k2, (((u64)__float_as_uint(t.z)) << 12) | (c0 + 2));
        if (x3) k3 = umin64(k3, (((u64)__float_as_uint(t.w)) << 12) | (c0 + 3));
        if (j < 12) {
            w[s] = row4[lane + 64 * (j + 4)];
            if (!first) cu[s] = c4[lane + 64 * (j + 4)];
            __builtin_amdgcn_sched_barrier(0);
        }
    }
    u64 kmin = umin64(umin64(k0, k1), umin64(k2, k3));
    #pragma unroll
    for (int off = 1; off <= 32; off <<= 1)
        kmin = umin64(kmin, shfl_xor_u64(kmin, off));
    if (lane == 0 && kmin != INFK) {
        u32 u  = (u32)kmin & 0xFFFu;
        u64 wb = kmin >> 12;
        u32 lo = min((u32)v, u), hi = max((u32)v, u);
        u64 g  = (wb << 24) | ((u64)lo << 12) | (u64)hi;
        if (first) {
            ws->best[m][v]  = g;
            ws->comp[m][v]  = (u32)v;
            ws->edges[m][v] = ((u32)v << 12) | (u32)v;
        } else if (g < ws->best[m][cv]) {
            atomicMin(&ws->best[m][cv], g);
        }
    }
    if (first && threadIdx.x == 0 && (blockIdx.x & 1023) == 0)
        ws->ncomp[m] = (u32)N;
}

// ---- hook: resolve 2-cycles, record edges (slot = dying root id),
// pointer-jump (early exit), relabel, reset best. One 1024-thread block per
// matrix. fin: also run the fused epilogue (even on the dead path). ----
__launch_bounds__(1024, 1)
__global__ void hook_k(const float* __restrict__ d1, const float* __restrict__ d2,
                       Ws* __restrict__ ws, float* __restrict__ out, int fin) {
    const int m = blockIdx.x;
    const int tid = threadIdx.x;
    const int lane = tid & 63, wave = tid >> 6;

    __shared__ u32 compL[N];
    __shared__ u32 nxtA[N];
    __shared__ u32 nxtB[N];
    __shared__ u32 red[16];
    __shared__ float fpart[16];

    if (ws->ncomp[m] > 1u) {
        u32* __restrict__ gcomp = ws->comp[m];
        u64* __restrict__ best  = ws->best[m];

        {
            uint4* dst = (uint4*)compL;
            const uint4* src = (const uint4*)gcomp;
            if (tid < N / 4) dst[tid] = src[tid];
        }
        __syncthreads();

        bool isroot[4];
        u64  bkey[4];

        #pragma unroll
        for (int k = 0; k < 4; ++k) {
            int i = tid + k * 1024;
            u32 x = (u32)i;
            bool r = (compL[i] == (u32)i);
            isroot[k] = r;
            u64 g = 0;
            if (r) {
                g = best[i];
                u32 lo = (u32)(g >> 12) & 0xFFFu;
                u32 hi = (u32)g & 0xFFFu;
                u32 cl = compL[lo], ch = compL[hi];
                x = (cl == (u32)i) ? ch : cl;
            }
            bkey[k] = g;
            nxtA[i] = x;
        }
        __syncthreads();

        #pragma unroll
        for (int k = 0; k < 4; ++k) {
            int i = tid + k * 1024;
            u32 nn = (u32)i;
            if (isroot[k]) {
                u32 o = nxtA[i];
                bool mutual = (nxtA[o] == (u32)i);
                nn = (mutual && ((u32)i < o)) ? (u32)i : o;
                if (nn != (u32)i)
                    ws->edges[m][i] = (u32)(bkey[k] & 0xFFFFFFu);
            }
            nxtB[i] = nn;
        }
        __syncthreads();

        // pointer jumping with early exit (typical depth <= 4)
        for (int s = 0; s < 12; ++s) {
            u32 changed = 0;
            #pragma unroll
            for (int k = 0; k < 4; ++k) {
                int i = tid + k * 1024;
                u32 a = nxtB[i];
                u32 t = nxtB[a];
                if (t != a) changed = 1u;
                nxtB[i] = t;
            }
            if (!__syncthreads_or((int)changed)) break;
        }

        u32 cnt = 0;
        #pragma unroll
        for (int k = 0; k < 4; ++k) {
            int i = tid + k * 1024;
            if (isroot[k] && nxtB[i] == (u32)i) cnt++;
        }
        #pragma unroll
        for (int off = 32; off >= 1; off >>= 1) cnt += (u32)__shfl_down((int)cnt, off, 64);
        if (lane == 0) red[wave] = cnt;
        __syncthreads();

        #pragma unroll
        for (int k = 0; k < 4; ++k) {
            int i = tid + k * 1024;
            gcomp[i] = nxtB[compL[i]];
            if (isroot[k]) best[i] = INFK;
        }
        if (tid == 0) {
            u32 t = 0;
            #pragma unroll
            for (int w = 0; w < 16; ++w) t += red[w];
            ws->ncomp[m] = t;
        }
    }

    // ---- fused epilogue on the final round ----
    if (fin) {
        __syncthreads();
        float acc = 0.f;
        #pragma unroll
        for (int k = 0; k < 4; ++k) {
            int i = tid + k * 1024;
            u32 pk = ws->edges[m][i];
            u32 lo = (pk >> 12) & 0xFFFu, hi = pk & 0xFFFu;
            size_t off = (size_t)lo * N + hi;
            float df = d1[off] - d2[off];     // diagonal sentinel -> 0
            acc += df * df;
        }
        #pragma unroll
        for (int off = 32; off >= 1; off >>= 1) acc += __shfl_down(acc, off, 64);
        if (lane == 0) fpart[wave] = acc;
        __syncthreads();
        if (tid == 0) {
            float t = 0.f;
            #pragma unroll
            for (int w = 0; w < 16; ++w) t += fpart[w];
            atomicAdd(out, t);
        }
    }
}

extern "C" void kernel_launch(void* const* d_in, const int* in_sizes, int n_in,
                              void* d_out, int out_size, void* d_ws, size_t ws_size,
                              hipStream_t stream) {
    (void)in_sizes; (void)n_in; (void)out_size;
    const float* d1 = (const float*)d_in[0];
    const float* d2 = (const float*)d_in[1];
    float* out = (float*)d_out;
    Ws* ws = (Ws*)d_ws;
    const bool big = (ws_size >= sizeof(Ws));   // ~4.4 MB needed for bound table

    hipMemsetAsync(d_out, 0, sizeof(float), stream);
    for (int r = 0; r < NROUNDS; ++r) {
        if (big) {
            if (r == 0) scanA_k<<<dim3(2048), dim3(256), 0, stream>>>(d1, d2, ws);
            else        scan2_k<<<dim3(2048), dim3(256), 0, stream>>>(d1, d2, ws);
        } else {
            scanF_k<<<dim3(2048), dim3(256), 0, stream>>>(d1, d2, ws, r == 0 ? 1 : 0);
        }
        hook_k<<<dim3(2), dim3(1024), 0, stream>>>(d1, d2, ws, out, r == NROUNDS - 1 ? 1 : 0);
    }
}

// Round 3
// 413.206 us; speedup vs baseline: 1.0355x; 1.0355x over previous
//
#include <hip/hip_runtime.h>
#include <stdint.h>

// TopoSignature via parallel Boruvka MST. Round 14: revert r13's sched_barrier
// pinning (reproduced m141 failure: scan2 15->87us, total 428us) and attack
// the byte count instead.
//  - r13 counters: worst scan2 FETCH = 114.6 MB (~85% of both matrices) at
//    87us. Cause: bound blocks were mod-256 interleaved, so a need-lane's
//    rescan reads 16B per 64B line at 1KB stride -> up to 4x HBM
//    amplification in the heavy middle rounds.
//  - Fix: contiguous block ownership. Block L = cols [64L,64L+64). scanA's
//    coalesced load loop is UNCHANGED; at chunk j the 16-lane group g already
//    covers block b=4j+g, so a 4-step shfl_xor butterfly (off 1,2,4,8) gives
//    block mins in-loop; lane L retains block 4*(L&15)+(L>>4); bm store is a
//    permutation of a contiguous 512B range (coalesced). scan2 rescan becomes
//    a per-lane contiguous 1KB stream -> fetch == useful bytes.
// Lessons kept: kernel boundary = only cheap device-wide barrier (r8); no
// replicated hook (r10); NO source-level load pipelining (r12: compiler
// re-serializes; r13: sched_barrier(0) defeats waitcnt scheduling, m141).

#define N        4096
#define NROUNDS  12

typedef unsigned long long u64;
typedef uint32_t u32;

#define INFK (~0ull)

struct Ws {
    u64 best[2][N];      // per-component min outgoing edge key: (wbits<<24)|(lo<<12)|hi
    u32 comp[2][N];      // vertex -> component root label
    u32 edges[2][N];     // edge slot per vertex, (lo<<12)|hi; (i<<12)|i = none
    u32 ncomp[2];
    u32 pad[14];
    u64 bm[2][N * 64];   // per-row per-block bound keys: (wbits<<12)|col ; block L = cols [64L,64L+64)
};

__device__ __forceinline__ u64 umin64(u64 a, u64 b) { return a < b ? a : b; }

__device__ __forceinline__ u64 shfl_xor_u64(u64 x, int off) {
    u32 lo = (u32)x, hi = (u32)(x >> 32);
    lo = (u32)__shfl_xor((int)lo, off, 64);
    hi = (u32)__shfl_xor((int)hi, off, 64);
    return ((u64)hi << 32) | lo;
}

// ---- round 1 full scan + state init. One wave per row. Coalesced chunk
// loads; per-chunk 16-lane butterflies produce contiguous-block mins. ----
__launch_bounds__(256, 8)
__global__ void scanA_k(const float* __restrict__ d1, const float* __restrict__ d2,
                        Ws* __restrict__ ws) {
    const int m = blockIdx.x >> 10;
    const int wave = threadIdx.x >> 6, lane = threadIdx.x & 63;
    const int v = ((blockIdx.x & 1023) << 2) + wave;
    const float4* __restrict__ row4 = (const float4*)((m ? d2 : d1) + (size_t)v * N);

    const u32 uv = (u32)v;
    u64 rowacc = INFK;   // running row min
    u64 kept   = INFK;   // this lane's retained block min
    #pragma unroll
    for (int j = 0; j < 16; ++j) {
        const int c = lane + 64 * j;              // coalesced: wave covers cols [256j,256j+256)
        float4 w = row4[c];
        const u32 c0 = (u32)(4 * c);
        u64 k0 = (c0 + 0 != uv) ? ((((u64)__float_as_uint(w.x)) << 12) | (c0 + 0)) : INFK;
        u64 k1 = (c0 + 1 != uv) ? ((((u64)__float_as_uint(w.y)) << 12) | (c0 + 1)) : INFK;
        u64 k2 = (c0 + 2 != uv) ? ((((u64)__float_as_uint(w.z)) << 12) | (c0 + 2)) : INFK;
        u64 k3 = (c0 + 3 != uv) ? ((((u64)__float_as_uint(w.w)) << 12) | (c0 + 3)) : INFK;
        u64 lm = umin64(umin64(k0, k1), umin64(k2, k3));
        rowacc = umin64(rowacc, lm);
        // 16-lane-group butterfly: group g holds min of block b = 4j + g
        #pragma unroll
        for (int off = 1; off <= 8; off <<= 1)
            lm = umin64(lm, shfl_xor_u64(lm, off));
        if ((lane & 15) == j) kept = lm;          // lane L keeps block 4*(L&15)+(L>>4)
    }
    // permuted-but-contiguous 512 B store: slot b gets block b's min
    ws->bm[m][(size_t)v * 64 + (4 * (lane & 15) + (lane >> 4))] = kept;

    u64 rowmin = rowacc;
    #pragma unroll
    for (int off = 1; off <= 32; off <<= 1)
        rowmin = umin64(rowmin, shfl_xor_u64(rowmin, off));

    if (lane == 0) {
        u32 u  = (u32)rowmin & 0xFFFu;
        u64 wb = rowmin >> 12;
        u32 lo = min(uv, u), hi = max(uv, u);
        ws->best[m][v]  = (wb << 24) | ((u64)lo << 12) | (u64)hi;  // comp==v, unique writer
        ws->comp[m][v]  = uv;                                       // init fold
        ws->edges[m][v] = (uv << 12) | uv;                          // diag sentinel
    }
    if (threadIdx.x == 0 && (blockIdx.x & 1023) == 0)
        ws->ncomp[m] = (u32)N;
}

// ---- rounds 2+: bound-table scan. One wave per row; lane L owns contiguous
// block L = cols [64L,64L+64); rescan is a per-lane contiguous 1 KB stream. ----
__launch_bounds__(256, 8)
__global__ void scan2_k(const float* __restrict__ d1, const float* __restrict__ d2,
                        Ws* __restrict__ ws) {
    const int m = blockIdx.x >> 10;
    if (ws->ncomp[m] <= 1u) return;
    const int wave = threadIdx.x >> 6, lane = threadIdx.x & 63;
    const int v = ((blockIdx.x & 1023) << 2) + wave;

    const float* __restrict__ dm = m ? d2 : d1;
    const u32*   __restrict__ cm = ws->comp[m];
    u64* __restrict__ bmrow = ws->bm[m] + (size_t)v * 64;

    const u32 cv = cm[v];
    u64 key = bmrow[lane];
    bool cross = false;
    if (key != INFK) cross = (cm[(u32)key & 0xFFFu] != cv);

    // best cross candidate among stored block mins (exact entries)
    u64 kb = cross ? key : INFK;
    #pragma unroll
    for (int off = 1; off <= 32; off <<= 1)
        kb = umin64(kb, shfl_xor_u64(kb, off));

    // intra bound undercutting kb -> block may hide a smaller cross entry
    const bool need = (!cross) && (key < kb);
    u64 nm = INFK;
    if (need) {
        const float4* __restrict__ row4 = (const float4*)(dm + (size_t)v * N);
        const uint4*  __restrict__ c4   = (const uint4*)cm;
        const int base = lane * 16;               // contiguous 1 KB slice
        u64 n0 = INFK, n1 = INFK, n2 = INFK, n3 = INFK;
        #pragma unroll
        for (int j = 0; j < 16; ++j) {
            float4 w  = row4[base + j];
            uint4  cu = c4[base + j];
            const u32 c0 = (u32)(4 * (base + j));
            if (cu.x != cv) n0 = umin64(n0, (((u64)__float_as_uint(w.x)) << 12) | (c0 + 0));
            if (cu.y != cv) n1 = umin64(n1, (((u64)__float_as_uint(w.y)) << 12) | (c0 + 1));
            if (cu.z != cv) n2 = umin64(n2, (((u64)__float_as_uint(w.z)) << 12) | (c0 + 2));
            if (cu.w != cv) n3 = umin64(n3, (((u64)__float_as_uint(w.w)) << 12) | (c0 + 3));
        }
        nm = umin64(umin64(n0, n1), umin64(n2, n3));
        bmrow[lane] = nm;    // tightened bound: block's current min-cross key (may be INFK)
    }
    u64 kb2 = need ? nm : INFK;
    #pragma unroll
    for (int off = 1; off <= 32; off <<= 1)
        kb2 = umin64(kb2, shfl_xor_u64(kb2, off));

    u64 fin = umin64(kb, kb2);
    if (lane == 0 && fin != INFK) {
        u32 u  = (u32)fin & 0xFFFu;
        u64 wb = fin >> 12;
        u32 lo = min((u32)v, u), hi = max((u32)v, u);
        u64 g  = (wb << 24) | ((u64)lo << 12) | (u64)hi;
        if (g < ws->best[m][cv])
            atomicMin(&ws->best[m][cv], g);
    }
}

// ---- fallback full scan (ws too small for bound table) ----
__launch_bounds__(256, 8)
__global__ void scanF_k(const float* __restrict__ d1, const float* __restrict__ d2,
                        Ws* __restrict__ ws, int first) {
    const int m = blockIdx.x >> 10;
    if (!first && ws->ncomp[m] <= 1u) return;
    const int wave = threadIdx.x >> 6, lane = threadIdx.x & 63;
    const int v = ((blockIdx.x & 1023) << 2) + wave;
    const float* __restrict__ dm = m ? d2 : d1;
    const u32*   __restrict__ cm = ws->comp[m];
    const float4* __restrict__ row4 = (const float4*)(dm + (size_t)v * N);
    const uint4*  __restrict__ c4   = (const uint4*)cm;
    const u32 cv = first ? (u32)v : cm[v];
    u64 kmin = INFK;
    #pragma unroll
    for (int j = 0; j < 16; ++j) {
        const int c = lane + 64 * j;
        float4 w = row4[c];
        uint4 cu;
        if (!first) cu = c4[c];
        const u32 c0 = (u32)(4 * c);
        bool x0, x1, x2, x3;
        if (first) {
            x0 = (c0+0 != cv); x1 = (c0+1 != cv); x2 = (c0+2 != cv); x3 = (c0+3 != cv);
        } else {
            x0 = (cu.x != cv); x1 = (cu.y != cv); x2 = (cu.z != cv); x3 = (cu.w != cv);
        }
        if (x0) kmin = umin64(kmin, (((u64)__float_as_uint(w.x)) << 12) | (c0 + 0));
        if (x1) kmin = umin64(kmin, (((u64)__float_as_uint(w.y)) << 12) | (c0 + 1));
        if (x2) kmin = umin64(kmin, (((u64)__float_as_uint(w.z)) << 12) | (c0 + 2));
        if (x3) kmin = umin64(kmin, (((u64)__float_as_uint(w.w)) << 12) | (c0 + 3));
    }
    #pragma unroll
    for (int off = 1; off <= 32; off <<= 1)
        kmin = umin64(kmin, shfl_xor_u64(kmin, off));
    if (lane == 0 && kmin != INFK) {
        u32 u  = (u32)kmin & 0xFFFu;
        u64 wb = kmin >> 12;
        u32 lo = min((u32)v, u), hi = max((u32)v, u);
        u64 g  = (wb << 24) | ((u64)lo << 12) | (u64)hi;
        if (first) {
            ws->best[m][v]  = g;
            ws->comp[m][v]  = (u32)v;
            ws->edges[m][v] = ((u32)v << 12) | (u32)v;
        } else if (g < ws->best[m][cv]) {
            atomicMin(&ws->best[m][cv], g);
        }
    }
    if (first && threadIdx.x == 0 && (blockIdx.x & 1023) == 0)
        ws->ncomp[m] = (u32)N;
}

// ---- hook: resolve 2-cycles, record edges (slot = dying root id),
// pointer-jump (early exit), relabel, reset best. One 1024-thread block per
// matrix. fin: also run the fused epilogue (even on the dead path). ----
__launch_bounds__(1024, 1)
__global__ void hook_k(const float* __restrict__ d1, const float* __restrict__ d2,
                       Ws* __restrict__ ws, float* __restrict__ out, int fin) {
    const int m = blockIdx.x;
    const int tid = threadIdx.x;
    const int lane = tid & 63, wave = tid >> 6;

    __shared__ u32 compL[N];
    __shared__ u32 nxtA[N];
    __shared__ u32 nxtB[N];
    __shared__ u32 red[16];
    __shared__ float fpart[16];

    if (ws->ncomp[m] > 1u) {
        u32* __restrict__ gcomp = ws->comp[m];
        u64* __restrict__ best  = ws->best[m];

        {
            uint4* dst = (uint4*)compL;
            const uint4* src = (const uint4*)gcomp;
            if (tid < N / 4) dst[tid] = src[tid];
        }
        __syncthreads();

        bool isroot[4];
        u64  bkey[4];

        #pragma unroll
        for (int k = 0; k < 4; ++k) {
            int i = tid + k * 1024;
            u32 x = (u32)i;
            bool r = (compL[i] == (u32)i);
            isroot[k] = r;
            u64 g = 0;
            if (r) {
                g = best[i];
                u32 lo = (u32)(g >> 12) & 0xFFFu;
                u32 hi = (u32)g & 0xFFFu;
                u32 cl = compL[lo], ch = compL[hi];
                x = (cl == (u32)i) ? ch : cl;
            }
            bkey[k] = g;
            nxtA[i] = x;
        }
        __syncthreads();

        #pragma unroll
        for (int k = 0; k < 4; ++k) {
            int i = tid + k * 1024;
            u32 nn = (u32)i;
            if (isroot[k]) {
                u32 o = nxtA[i];
                bool mutual = (nxtA[o] == (u32)i);
                nn = (mutual && ((u32)i < o)) ? (u32)i : o;
                if (nn != (u32)i)
                    ws->edges[m][i] = (u32)(bkey[k] & 0xFFFFFFu);
            }
            nxtB[i] = nn;
        }
        __syncthreads();

        // pointer jumping with early exit (typical depth <= 4)
        for (int s = 0; s < 12; ++s) {
            u32 changed = 0;
            #pragma unroll
            for (int k = 0; k < 4; ++k) {
                int i = tid + k * 1024;
                u32 a = nxtB[i];
                u32 t = nxtB[a];
                if (t != a) changed = 1u;
                nxtB[i] = t;
            }
            if (!__syncthreads_or((int)changed)) break;
        }

        u32 cnt = 0;
        #pragma unroll
        for (int k = 0; k < 4; ++k) {
            int i = tid + k * 1024;
            if (isroot[k] && nxtB[i] == (u32)i) cnt++;
        }
        #pragma unroll
        for (int off = 32; off >= 1; off >>= 1) cnt += (u32)__shfl_down((int)cnt, off, 64);
        if (lane == 0) red[wave] = cnt;
        __syncthreads();

        #pragma unroll
        for (int k = 0; k < 4; ++k) {
            int i = tid + k * 1024;
            gcomp[i] = nxtB[compL[i]];
            if (isroot[k]) best[i] = INFK;
        }
        if (tid == 0) {
            u32 t = 0;
            #pragma unroll
            for (int w = 0; w < 16; ++w) t += red[w];
            ws->ncomp[m] = t;
        }
    }

    // ---- fused epilogue on the final round ----
    if (fin) {
        __syncthreads();
        float acc = 0.f;
        #pragma unroll
        for (int k = 0; k < 4; ++k) {
            int i = tid + k * 1024;
            u32 pk = ws->edges[m][i];
            u32 lo = (pk >> 12) & 0xFFFu, hi = pk & 0xFFFu;
            size_t off = (size_t)lo * N + hi;
            float df = d1[off] - d2[off];     // diagonal sentinel -> 0
            acc += df * df;
        }
        #pragma unroll
        for (int off = 32; off >= 1; off >>= 1) acc += __shfl_down(acc, off, 64);
        if (lane == 0) fpart[wave] = acc;
        __syncthreads();
        if (tid == 0) {
            float t = 0.f;
            #pragma unroll
            for (int w = 0; w < 16; ++w) t += fpart[w];
            atomicAdd(out, t);
        }
    }
}

extern "C" void kernel_launch(void* const* d_in, const int* in_sizes, int n_in,
                              void* d_out, int out_size, void* d_ws, size_t ws_size,
                              hipStream_t stream) {
    (void)in_sizes; (void)n_in; (void)out_size;
    const float* d1 = (const float*)d_in[0];
    const float* d2 = (const float*)d_in[1];
    float* out = (float*)d_out;
    Ws* ws = (Ws*)d_ws;
    const bool big = (ws_size >= sizeof(Ws));   // ~4.4 MB needed for bound table

    hipMemsetAsync(d_out, 0, sizeof(float), stream);
    for (int r = 0; r < NROUNDS; ++r) {
        if (big) {
            if (r == 0) scanA_k<<<dim3(2048), dim3(256), 0, stream>>>(d1, d2, ws);
            else        scan2_k<<<dim3(2048), dim3(256), 0, stream>>>(d1, d2, ws);
        } else {
            scanF_k<<<dim3(2048), dim3(256), 0, stream>>>(d1, d2, ws, r == 0 ? 1 : 0);
        }
        hook_k<<<dim3(2), dim3(1024), 0, stream>>>(d1, d2, ws, out, r == NROUNDS - 1 ? 1 : 0);
    }
}

// Round 4
// 271.113 us; speedup vs baseline: 1.5782x; 1.5241x over previous
//
#include <hip/hip_runtime.h>
#include <stdint.h>

// TopoSignature via parallel Boruvka MST. Round 15: line-dense bound bins,
// spill-proof.
//  - r14 post-mortem: scanA WRITE_SIZE 108 MB = scratch spill (16 hoisted
//    float4s, 256 B/thread) triggered by the in-loop 16-lane butterfly's long
//    dependent chains. Ownership idea untested, implementation poisoned it.
//  - r15: bin b = cache lines ≡ b (mod 64) (16 cols each). scanA keeps r11's
//    EXACT coalesced loads; per chunk a 2-step shfl (cluster of 4 lanes =
//    one line) + phased retention (lane 4q+t takes j≡t mod 4 -> bin q+16t).
//    #pragma unroll 4 caps in-flight loads (anti-spill). Row min = butterfly
//    over bin accs. scan2 rescan of bin L = 4x one full 64B line (1 KB apart)
//    -> fetch == useful bytes (r13 measured 114 MB/dispatch from 4x line
//    amplification). Rescan outer loop unroll 1 (anti-spill: 4+4 loads max).
// Lessons kept: kernel boundary = only cheap device-wide barrier (r8); no
// replicated hook (r10); no sched_barrier pinning (r13/m141); no full-width
// load batching (r12/r14: compiler hoist->spill).

#define N        4096
#define NROUNDS  12

typedef unsigned long long u64;
typedef uint32_t u32;

#define INFK (~0ull)

struct Ws {
    u64 best[2][N];      // per-component min outgoing edge key: (wbits<<24)|(lo<<12)|hi
    u32 comp[2][N];      // vertex -> component root label
    u32 edges[2][N];     // edge slot per vertex, (lo<<12)|hi; (i<<12)|i = none
    u32 ncomp[2];
    u32 pad[14];
    u64 bm[2][N * 64];   // per-row per-bin bound keys: (wbits<<12)|col ;
                         // bin b = cols c with ((c>>4) & 63) == b (line-dense)
};

__device__ __forceinline__ u64 umin64(u64 a, u64 b) { return a < b ? a : b; }

__device__ __forceinline__ u64 shfl_xor_u64(u64 x, int off) {
    u32 lo = (u32)x, hi = (u32)(x >> 32);
    lo = (u32)__shfl_xor((int)lo, off, 64);
    hi = (u32)__shfl_xor((int)hi, off, 64);
    return ((u64)hi << 32) | lo;
}

// ---- round 1 full scan + state init. One wave per row. r11's coalesced
// chunk loads; per-chunk 4-lane (one line) butterfly + phased retention. ----
__launch_bounds__(256, 8)
__global__ void scanA_k(const float* __restrict__ d1, const float* __restrict__ d2,
                        Ws* __restrict__ ws) {
    const int m = blockIdx.x >> 10;
    const int wave = threadIdx.x >> 6, lane = threadIdx.x & 63;
    const int v = ((blockIdx.x & 1023) << 2) + wave;
    const float4* __restrict__ row4 = (const float4*)((m ? d2 : d1) + (size_t)v * N);

    const u32 uv = (u32)v;
    const int t = lane & 3;          // retention phase of this lane
    u64 binacc = INFK;               // min over bin (lane>>2) + 16*t

    #pragma unroll 4
    for (int j = 0; j < 16; ++j) {
        const int c = lane + 64 * j;              // coalesced: wave covers cols [256j,256j+256)
        float4 w = row4[c];
        const u32 c0 = (u32)(4 * c);
        u64 k0 = (c0 + 0 != uv) ? ((((u64)__float_as_uint(w.x)) << 12) | (c0 + 0)) : INFK;
        u64 k1 = (c0 + 1 != uv) ? ((((u64)__float_as_uint(w.y)) << 12) | (c0 + 1)) : INFK;
        u64 k2 = (c0 + 2 != uv) ? ((((u64)__float_as_uint(w.z)) << 12) | (c0 + 2)) : INFK;
        u64 k3 = (c0 + 3 != uv) ? ((((u64)__float_as_uint(w.w)) << 12) | (c0 + 3)) : INFK;
        u64 lm = umin64(umin64(k0, k1), umin64(k2, k3));
        // cluster q=lane>>2 covers exactly line q+16j: 2-step butterfly
        lm = umin64(lm, shfl_xor_u64(lm, 1));
        lm = umin64(lm, shfl_xor_u64(lm, 2));
        // lane 4q+t retains chunks j==t (mod 4): all map to bin q+16t
        if ((j & 3) == t) binacc = umin64(binacc, lm);
    }
    // slot b = (lane>>2) + 16*(lane&3): permuted-but-contiguous 512 B store
    ws->bm[m][(size_t)v * 64 + ((lane >> 2) + 16 * t)] = binacc;

    // 64 bins partition the row -> row min = butterfly over bin accs
    u64 rowmin = binacc;
    #pragma unroll
    for (int off = 1; off <= 32; off <<= 1)
        rowmin = umin64(rowmin, shfl_xor_u64(rowmin, off));

    if (lane == 0) {
        u32 u  = (u32)rowmin & 0xFFFu;
        u64 wb = rowmin >> 12;
        u32 lo = min(uv, u), hi = max(uv, u);
        ws->best[m][v]  = (wb << 24) | ((u64)lo << 12) | (u64)hi;  // comp==v, unique writer
        ws->comp[m][v]  = uv;                                       // init fold
        ws->edges[m][v] = (uv << 12) | uv;                          // diag sentinel
    }
    if (threadIdx.x == 0 && (blockIdx.x & 1023) == 0)
        ws->ncomp[m] = (u32)N;
}

// ---- rounds 2+: bound-table scan. One wave per row; lane L owns bin L =
// lines {L, L+64, L+128, L+192}; rescan reads 4 full 64 B lines. ----
__launch_bounds__(256, 8)
__global__ void scan2_k(const float* __restrict__ d1, const float* __restrict__ d2,
                        Ws* __restrict__ ws) {
    const int m = blockIdx.x >> 10;
    if (ws->ncomp[m] <= 1u) return;
    const int wave = threadIdx.x >> 6, lane = threadIdx.x & 63;
    const int v = ((blockIdx.x & 1023) << 2) + wave;

    const float* __restrict__ dm = m ? d2 : d1;
    const u32*   __restrict__ cm = ws->comp[m];
    u64* __restrict__ bmrow = ws->bm[m] + (size_t)v * 64;

    const u32 cv = cm[v];
    u64 key = bmrow[lane];
    bool cross = false;
    if (key != INFK) cross = (cm[(u32)key & 0xFFFu] != cv);

    // best cross candidate among stored bin mins (exact entries)
    u64 kb = cross ? key : INFK;
    #pragma unroll
    for (int off = 1; off <= 32; off <<= 1)
        kb = umin64(kb, shfl_xor_u64(kb, off));

    // intra bound undercutting kb -> bin may hide a smaller cross entry
    const bool need = (!cross) && (key < kb);
    u64 nm = INFK;
    if (need) {
        const float4* __restrict__ row4 = (const float4*)(dm + (size_t)v * N);
        const uint4*  __restrict__ c4   = (const uint4*)cm;
        u64 n0 = INFK, n1 = INFK, n2 = INFK, n3 = INFK;
        #pragma unroll 1
        for (int s = 0; s < 4; ++s) {
            const int fb = 4 * lane + 256 * s;    // one full 64 B line
            #pragma unroll
            for (int k = 0; k < 4; ++k) {
                float4 w  = row4[fb + k];
                uint4  cu = c4[fb + k];
                const u32 c0 = (u32)(4 * (fb + k));
                if (cu.x != cv) n0 = umin64(n0, (((u64)__float_as_uint(w.x)) << 12) | (c0 + 0));
                if (cu.y != cv) n1 = umin64(n1, (((u64)__float_as_uint(w.y)) << 12) | (c0 + 1));
                if (cu.z != cv) n2 = umin64(n2, (((u64)__float_as_uint(w.z)) << 12) | (c0 + 2));
                if (cu.w != cv) n3 = umin64(n3, (((u64)__float_as_uint(w.w)) << 12) | (c0 + 3));
            }
        }
        nm = umin64(umin64(n0, n1), umin64(n2, n3));
        bmrow[lane] = nm;    // tightened bound: bin's current min-cross key (may be INFK)
    }
    u64 kb2 = need ? nm : INFK;
    #pragma unroll
    for (int off = 1; off <= 32; off <<= 1)
        kb2 = umin64(kb2, shfl_xor_u64(kb2, off));

    u64 fin = umin64(kb, kb2);
    if (lane == 0 && fin != INFK) {
        u32 u  = (u32)fin & 0xFFFu;
        u64 wb = fin >> 12;
        u32 lo = min((u32)v, u), hi = max((u32)v, u);
        u64 g  = (wb << 24) | ((u64)lo << 12) | (u64)hi;
        if (g < ws->best[m][cv])
            atomicMin(&ws->best[m][cv], g);
    }
}

// ---- fallback full scan (ws too small for bound table) ----
__launch_bounds__(256, 8)
__global__ void scanF_k(const float* __restrict__ d1, const float* __restrict__ d2,
                        Ws* __restrict__ ws, int first) {
    const int m = blockIdx.x >> 10;
    if (!first && ws->ncomp[m] <= 1u) return;
    const int wave = threadIdx.x >> 6, lane = threadIdx.x & 63;
    const int v = ((blockIdx.x & 1023) << 2) + wave;
    const float* __restrict__ dm = m ? d2 : d1;
    const u32*   __restrict__ cm = ws->comp[m];
    const float4* __restrict__ row4 = (const float4*)(dm + (size_t)v * N);
    const uint4*  __restrict__ c4   = (const uint4*)cm;
    const u32 cv = first ? (u32)v : cm[v];
    u64 kmin = INFK;
    #pragma unroll
    for (int j = 0; j < 16; ++j) {
        const int c = lane + 64 * j;
        float4 w = row4[c];
        uint4 cu;
        if (!first) cu = c4[c];
        const u32 c0 = (u32)(4 * c);
        bool x0, x1, x2, x3;
        if (first) {
            x0 = (c0+0 != cv); x1 = (c0+1 != cv); x2 = (c0+2 != cv); x3 = (c0+3 != cv);
        } else {
            x0 = (cu.x != cv); x1 = (cu.y != cv); x2 = (cu.z != cv); x3 = (cu.w != cv);
        }
        if (x0) kmin = umin64(kmin, (((u64)__float_as_uint(w.x)) << 12) | (c0 + 0));
        if (x1) kmin = umin64(kmin, (((u64)__float_as_uint(w.y)) << 12) | (c0 + 1));
        if (x2) kmin = umin64(kmin, (((u64)__float_as_uint(w.z)) << 12) | (c0 + 2));
        if (x3) kmin = umin64(kmin, (((u64)__float_as_uint(w.w)) << 12) | (c0 + 3));
    }
    #pragma unroll
    for (int off = 1; off <= 32; off <<= 1)
        kmin = umin64(kmin, shfl_xor_u64(kmin, off));
    if (lane == 0 && kmin != INFK) {
        u32 u  = (u32)kmin & 0xFFFu;
        u64 wb = kmin >> 12;
        u32 lo = min((u32)v, u), hi = max((u32)v, u);
        u64 g  = (wb << 24) | ((u64)lo << 12) | (u64)hi;
        if (first) {
            ws->best[m][v]  = g;
            ws->comp[m][v]  = (u32)v;
            ws->edges[m][v] = ((u32)v << 12) | (u32)v;
        } else if (g < ws->best[m][cv]) {
            atomicMin(&ws->best[m][cv], g);
        }
    }
    if (first && threadIdx.x == 0 && (blockIdx.x & 1023) == 0)
        ws->ncomp[m] = (u32)N;
}

// ---- hook: resolve 2-cycles, record edges (slot = dying root id),
// pointer-jump (early exit), relabel, reset best. One 1024-thread block per
// matrix. fin: also run the fused epilogue (even on the dead path). ----
__launch_bounds__(1024, 1)
__global__ void hook_k(const float* __restrict__ d1, const float* __restrict__ d2,
                       Ws* __restrict__ ws, float* __restrict__ out, int fin) {
    const int m = blockIdx.x;
    const int tid = threadIdx.x;
    const int lane = tid & 63, wave = tid >> 6;

    __shared__ u32 compL[N];
    __shared__ u32 nxtA[N];
    __shared__ u32 nxtB[N];
    __shared__ u32 red[16];
    __shared__ float fpart[16];

    if (ws->ncomp[m] > 1u) {
        u32* __restrict__ gcomp = ws->comp[m];
        u64* __restrict__ best  = ws->best[m];

        {
            uint4* dst = (uint4*)compL;
            const uint4* src = (const uint4*)gcomp;
            if (tid < N / 4) dst[tid] = src[tid];
        }
        __syncthreads();

        bool isroot[4];
        u64  bkey[4];

        #pragma unroll
        for (int k = 0; k < 4; ++k) {
            int i = tid + k * 1024;
            u32 x = (u32)i;
            bool r = (compL[i] == (u32)i);
            isroot[k] = r;
            u64 g = 0;
            if (r) {
                g = best[i];
                u32 lo = (u32)(g >> 12) & 0xFFFu;
                u32 hi = (u32)g & 0xFFFu;
                u32 cl = compL[lo], ch = compL[hi];
                x = (cl == (u32)i) ? ch : cl;
            }
            bkey[k] = g;
            nxtA[i] = x;
        }
        __syncthreads();

        #pragma unroll
        for (int k = 0; k < 4; ++k) {
            int i = tid + k * 1024;
            u32 nn = (u32)i;
            if (isroot[k]) {
                u32 o = nxtA[i];
                bool mutual = (nxtA[o] == (u32)i);
                nn = (mutual && ((u32)i < o)) ? (u32)i : o;
                if (nn != (u32)i)
                    ws->edges[m][i] = (u32)(bkey[k] & 0xFFFFFFu);
            }
            nxtB[i] = nn;
        }
        __syncthreads();

        // pointer jumping with early exit (typical depth <= 4)
        for (int s = 0; s < 12; ++s) {
            u32 changed = 0;
            #pragma unroll
            for (int k = 0; k < 4; ++k) {
                int i = tid + k * 1024;
                u32 a = nxtB[i];
                u32 t = nxtB[a];
                if (t != a) changed = 1u;
                nxtB[i] = t;
            }
            if (!__syncthreads_or((int)changed)) break;
        }

        u32 cnt = 0;
        #pragma unroll
        for (int k = 0; k < 4; ++k) {
            int i = tid + k * 1024;
            if (isroot[k] && nxtB[i] == (u32)i) cnt++;
        }
        #pragma unroll
        for (int off = 32; off >= 1; off >>= 1) cnt += (u32)__shfl_down((int)cnt, off, 64);
        if (lane == 0) red[wave] = cnt;
        __syncthreads();

        #pragma unroll
        for (int k = 0; k < 4; ++k) {
            int i = tid + k * 1024;
            gcomp[i] = nxtB[compL[i]];
            if (isroot[k]) best[i] = INFK;
        }
        if (tid == 0) {
            u32 t = 0;
            #pragma unroll
            for (int w = 0; w < 16; ++w) t += red[w];
            ws->ncomp[m] = t;
        }
    }

    // ---- fused epilogue on the final round ----
    if (fin) {
        __syncthreads();
        float acc = 0.f;
        #pragma unroll
        for (int k = 0; k < 4; ++k) {
            int i = tid + k * 1024;
            u32 pk = ws->edges[m][i];
            u32 lo = (pk >> 12) & 0xFFFu, hi = pk & 0xFFFu;
            size_t off = (size_t)lo * N + hi;
            float df = d1[off] - d2[off];     // diagonal sentinel -> 0
            acc += df * df;
        }
        #pragma unroll
        for (int off = 32; off >= 1; off >>= 1) acc += __shfl_down(acc, off, 64);
        if (lane == 0) fpart[wave] = acc;
        __syncthreads();
        if (tid == 0) {
            float t = 0.f;
            #pragma unroll
            for (int w = 0; w < 16; ++w) t += fpart[w];
            atomicAdd(out, t);
        }
    }
}

extern "C" void kernel_launch(void* const* d_in, const int* in_sizes, int n_in,
                              void* d_out, int out_size, void* d_ws, size_t ws_size,
                              hipStream_t stream) {
    (void)in_sizes; (void)n_in; (void)out_size;
    const float* d1 = (const float*)d_in[0];
    const float* d2 = (const float*)d_in[1];
    float* out = (float*)d_out;
    Ws* ws = (Ws*)d_ws;
    const bool big = (ws_size >= sizeof(Ws));   // ~4.4 MB needed for bound table

    hipMemsetAsync(d_out, 0, sizeof(float), stream);
    for (int r = 0; r < NROUNDS; ++r) {
        if (big) {
            if (r == 0) scanA_k<<<dim3(2048), dim3(256), 0, stream>>>(d1, d2, ws);
            else        scan2_k<<<dim3(2048), dim3(256), 0, stream>>>(d1, d2, ws);
        } else {
            scanF_k<<<dim3(2048), dim3(256), 0, stream>>>(d1, d2, ws, r == 0 ? 1 : 0);
        }
        hook_k<<<dim3(2), dim3(1024), 0, stream>>>(d1, d2, ws, out, r == NROUNDS - 1 ? 1 : 0);
    }
}